// Round 1
// baseline (639.626 us; speedup 1.0000x reference)
//
#include <hip/hip_runtime.h>
#include <hip/hip_bf16.h>

// Problem constants
#define NB 4
#define NT 256
#define NU 100
#define NH 512      // H_ENC = H_DEC = 512
#define NI 512      // INNER
#define NV 1024     // VOCAB
// M = NB*NT*NU = 102400 joint rows

typedef __attribute__((ext_vector_type(4))) float f32x4;
typedef __attribute__((ext_vector_type(8))) __bf16 bf16x8;

// round-to-nearest-even f32 -> bf16 bits
static __device__ __forceinline__ unsigned int f2bf(float f) {
  unsigned int u = __float_as_uint(f);
  return (u + 0x7FFFu + ((u >> 16) & 1u)) >> 16;
}

// ---------------------------------------------------------------------------
// P[r][i] = sum_h A[r][h] * W1[i][colOff + h]   (A: Mrows x 512, W1: 512 x 1024)
// fp32, 64x64 tile, BK=16
// ---------------------------------------------------------------------------
__global__ __launch_bounds__(256) void proj_kernel(
    const float* __restrict__ A, const float* __restrict__ W1,
    float* __restrict__ P, int Mrows, int colOff) {
  __shared__ float As[64][17];
  __shared__ float Bs[64][17];
  const int tx = threadIdx.x;
  const int row0 = blockIdx.x * 64, col0 = blockIdx.y * 64;
  const int tr = tx >> 4, tc = tx & 15;   // 16x16 threads, 4x4 each
  const int lr = tx >> 2, lc = (tx & 3) * 4;
  float acc[4][4] = {};
  for (int k0 = 0; k0 < NH; k0 += 16) {
    float4 av = make_float4(0.f, 0.f, 0.f, 0.f);
    if (row0 + lr < Mrows)
      av = *(const float4*)(A + (size_t)(row0 + lr) * NH + k0 + lc);
    float4 bv = *(const float4*)(W1 + (size_t)(col0 + lr) * (NH + NH) + colOff + k0 + lc);
    As[lr][lc] = av.x; As[lr][lc + 1] = av.y; As[lr][lc + 2] = av.z; As[lr][lc + 3] = av.w;
    Bs[lr][lc] = bv.x; Bs[lr][lc + 1] = bv.y; Bs[lr][lc + 2] = bv.z; Bs[lr][lc + 3] = bv.w;
    __syncthreads();
#pragma unroll
    for (int kk = 0; kk < 16; ++kk) {
      float a4[4], b4[4];
#pragma unroll
      for (int i = 0; i < 4; ++i) { a4[i] = As[tr * 4 + i][kk]; b4[i] = Bs[tc * 4 + i][kk]; }
#pragma unroll
      for (int i = 0; i < 4; ++i)
#pragma unroll
        for (int j = 0; j < 4; ++j) acc[i][j] = fmaf(a4[i], b4[j], acc[i][j]);
    }
    __syncthreads();
  }
#pragma unroll
  for (int i = 0; i < 4; ++i) {
    int r = row0 + tr * 4 + i;
    if (r < Mrows) {
#pragma unroll
      for (int j = 0; j < 4; ++j)
        P[(size_t)r * NI + col0 + tc * 4 + j] = acc[i][j];
    }
  }
}

// ---------------------------------------------------------------------------
// W2 f32 -> bf16 bits (1024x512 elements), 4 per thread
// ---------------------------------------------------------------------------
__global__ __launch_bounds__(256) void cvt_w2_kernel(const float* __restrict__ W2,
                                                     unsigned short* __restrict__ w2b) {
  int i = (blockIdx.x * 256 + threadIdx.x) * 4;
  float4 v = *(const float4*)(W2 + i);
  uint2 o;
  o.x = f2bf(v.x) | (f2bf(v.y) << 16);
  o.y = f2bf(v.z) | (f2bf(v.w) << 16);
  *(uint2*)(w2b + i) = o;
}

// ---------------------------------------------------------------------------
// Fused: hidden = tanh(pe + pd + b1) -> bf16 LDS tile (64 rows x 512),
// then joint[row][v] = hidden . W2[v][:] + b2[v] via mfma_f32_16x16x32_bf16.
// Block: 256 thr (4 waves, 2x2), 64-row tile, loops 8 col-tiles of 128 vocab.
// LDS swizzle: byte ^= ((row&7)<<4) — spreads ds_read_b128 across banks.
// ---------------------------------------------------------------------------
__global__ __launch_bounds__(256, 2) void joint_kernel(
    const float* __restrict__ pe, const float* __restrict__ pd,
    const float* __restrict__ b1, const unsigned short* __restrict__ w2b,
    const float* __restrict__ b2, float* __restrict__ out) {
  __shared__ unsigned short hidS[64 * 512];  // 64KB, swizzled rows of 1024B
  __shared__ unsigned short w2S[128 * 64];   // 16KB, swizzled rows of 128B
  const int tx = threadIdx.x;
  const int R0 = blockIdx.x * 64;

  // prefetch first W2 tile (ct=0, k0=0) into regs (pre-swizzled source order)
  uint4 pre[4];
#pragma unroll
  for (int q = 0; q < 4; ++q) {
    int gidx = tx + q * 256;          // 16B granule index, 1024 total
    int col = gidx >> 3;              // 0..127
    int kbl = (gidx & 7) ^ (col & 7); // logical k-block for this physical slot
    pre[q] = *(const uint4*)(w2b + (size_t)col * NI + kbl * 8);
  }

  // stage hidden tile: tanh(pe+pd+b1) -> bf16, swizzled
#pragma unroll 2
  for (int pass = 0; pass < 16; ++pass) {
    int idx = pass * 256 + tx;     // 4096 granules of 8 elements
    int row = idx >> 6;            // 0..63
    int i0 = (idx & 63) * 8;
    int g = R0 + row;
    int b = g / (NT * NU);
    int rem = g - b * (NT * NU);
    int t = rem / NU;
    int u = rem - t * NU;
    const float* peP = pe + (size_t)(b * NT + t) * NI + i0;
    const float* pdP = pd + (size_t)(b * NU + u) * NI + i0;
    float4 p0 = *(const float4*)peP;
    float4 p1 = *(const float4*)(peP + 4);
    float4 q0 = *(const float4*)pdP;
    float4 q1 = *(const float4*)(pdP + 4);
    float4 c0 = *(const float4*)(b1 + i0);
    float4 c1 = *(const float4*)(b1 + i0 + 4);
    uint4 pk;
    pk.x = f2bf(tanhf(p0.x + q0.x + c0.x)) | (f2bf(tanhf(p0.y + q0.y + c0.y)) << 16);
    pk.y = f2bf(tanhf(p0.z + q0.z + c0.z)) | (f2bf(tanhf(p0.w + q0.w + c0.w)) << 16);
    pk.z = f2bf(tanhf(p1.x + q1.x + c1.x)) | (f2bf(tanhf(p1.y + q1.y + c1.y)) << 16);
    pk.w = f2bf(tanhf(p1.z + q1.z + c1.z)) | (f2bf(tanhf(p1.w + q1.w + c1.w)) << 16);
    int bo = (row * 1024 + i0 * 2) ^ ((row & 7) << 4);
    *(uint4*)((char*)hidS + bo) = pk;
  }

  const int lane = tx & 63;
  const int w = tx >> 6;
  const int wr = w >> 1, wc = w & 1;      // 2x2 wave grid; wave tile 32 rows x 64 cols
  const int lr = lane & 15, lq = lane >> 4;

  for (int ct = 0; ct < 8; ++ct) {
    const int C0 = ct * 128;
    f32x4 acc[2][4];
#pragma unroll
    for (int rf = 0; rf < 2; ++rf)
#pragma unroll
      for (int cf = 0; cf < 4; ++cf)
#pragma unroll
        for (int z = 0; z < 4; ++z) acc[rf][cf][z] = 0.f;

    for (int ks = 0; ks < 8; ++ks) {
      const int k0 = ks * 64;
      __syncthreads();   // previous MFMA step done reading w2S
#pragma unroll
      for (int q = 0; q < 4; ++q)
        *(uint4*)((char*)w2S + (tx + q * 256) * 16) = pre[q];
      __syncthreads();
      // prefetch next tile into regs (latency hidden under MFMA below)
      int s = ct * 8 + ks + 1;
      if (s < 64) {
        int nct = s >> 3, nk0 = (s & 7) * 64;
#pragma unroll
        for (int q = 0; q < 4; ++q) {
          int gidx = tx + q * 256;
          int col = gidx >> 3;
          int kbl = (gidx & 7) ^ (col & 7);
          pre[q] = *(const uint4*)(w2b + (size_t)(nct * 128 + col) * NI + nk0 + kbl * 8);
        }
      }
#pragma unroll
      for (int kh = 0; kh < 64; kh += 32) {
        const int ki = k0 + kh + lq * 8;   // hidden i-index for A frag
        bf16x8 afr[2], bfr[4];
#pragma unroll
        for (int rf = 0; rf < 2; ++rf) {
          int row = wr * 32 + rf * 16 + lr;
          int bo = (row * 1024 + ki * 2) ^ ((row & 7) << 4);
          afr[rf] = *(const bf16x8*)((const char*)hidS + bo);
        }
#pragma unroll
        for (int cf = 0; cf < 4; ++cf) {
          int col = wc * 64 + cf * 16 + lr;
          int kk = kh + lq * 8;
          int bo = (col * 128 + kk * 2) ^ ((col & 7) << 4);
          bfr[cf] = *(const bf16x8*)((const char*)w2S + bo);
        }
#pragma unroll
        for (int rf = 0; rf < 2; ++rf)
#pragma unroll
          for (int cf = 0; cf < 4; ++cf)
            acc[rf][cf] = __builtin_amdgcn_mfma_f32_16x16x32_bf16(
                afr[rf], bfr[cf], acc[rf][cf], 0, 0, 0);
      }
    }

    // epilogue: add b2, store fp32
#pragma unroll
    for (int cf = 0; cf < 4; ++cf) {
      int col = C0 + wc * 64 + cf * 16 + lr;
      float bb = b2[col];
#pragma unroll
      for (int rf = 0; rf < 2; ++rf) {
#pragma unroll
        for (int j = 0; j < 4; ++j) {
          int grow = R0 + wr * 32 + rf * 16 + lq * 4 + j;
          out[(size_t)grow * NV + col] = acc[rf][cf][j] + bb;
        }
      }
    }
  }
}

extern "C" void kernel_launch(void* const* d_in, const int* in_sizes, int n_in,
                              void* d_out, int out_size, void* d_ws, size_t ws_size,
                              hipStream_t stream) {
  const float* enc = (const float*)d_in[0];
  const float* dec = (const float*)d_in[1];
  const float* W1  = (const float*)d_in[2];
  const float* b1  = (const float*)d_in[3];
  const float* W2  = (const float*)d_in[4];
  const float* b2  = (const float*)d_in[5];
  float* out = (float*)d_out;
  char* ws = (char*)d_ws;

  float* pe = (float*)ws;                              // 1024*512*4 = 2 MB
  float* pd = (float*)(ws + (2u << 20));               // 400*512*4  = 0.8 MB
  unsigned short* w2b = (unsigned short*)(ws + (3u << 20)); // 1 MB bf16

  // pe = enc @ W1[:, :512]^T   (rows = B*T = 1024)
  proj_kernel<<<dim3(16, 8), 256, 0, stream>>>(enc, W1, pe, NB * NT, 0);
  // pd = dec @ W1[:, 512:]^T   (rows = B*U = 400)
  proj_kernel<<<dim3(7, 8), 256, 0, stream>>>(dec, W1, pd, NB * NU, NH);
  // W2 -> bf16
  cvt_w2_kernel<<<512, 256, 0, stream>>>(W2, w2b);
  // fused tanh + joint GEMM + b2
  joint_kernel<<<1600, 256, 0, stream>>>(pe, pd, b1, w2b, b2, out);
}

// Round 2
// 331.957 us; speedup vs baseline: 1.9268x; 1.9268x over previous
//
#include <hip/hip_runtime.h>
#include <hip/hip_bf16.h>

// Problem constants
#define NB 4
#define NT 256
#define NU 100
#define NH 512      // H_ENC = H_DEC = 512
#define NI 512      // INNER
#define NV 1024     // VOCAB
#define MROWS (NB * NT * NU)   // 102400 joint rows

typedef __attribute__((ext_vector_type(4))) float f32x4;
typedef __attribute__((ext_vector_type(8))) __bf16 bf16x8;

// round-to-nearest-even f32 -> bf16 bits
static __device__ __forceinline__ unsigned int f2bf(float f) {
  unsigned int u = __float_as_uint(f);
  return (u + 0x7FFFu + ((u >> 16) & 1u)) >> 16;
}

// tanh(x) = 1 - 2/(1+e^{2x});  v_exp + v_rcp, ~1e-6 abs error (bf16 swamps it)
static __device__ __forceinline__ float fast_tanh(float x) {
  float e = __expf(2.f * x);
  return 1.f - 2.f * __builtin_amdgcn_rcpf(1.f + e);
}

// async global->LDS, 16B per lane
static __device__ __forceinline__ void gload16(const void* g, void* l) {
  __builtin_amdgcn_global_load_lds(
      (const __attribute__((address_space(1))) unsigned int*)(g),
      (__attribute__((address_space(3))) unsigned int*)(l), 16, 0, 0);
}

// ---------------------------------------------------------------------------
// P[r][i] = sum_h A[r][h] * W1[i][colOff + h]   (fp32, 64x64 tile, BK=16)
// ---------------------------------------------------------------------------
__global__ __launch_bounds__(256) void proj_kernel(
    const float* __restrict__ A, const float* __restrict__ W1,
    float* __restrict__ P, int Mrows, int colOff) {
  __shared__ float As[64][17];
  __shared__ float Bs[64][17];
  const int tx = threadIdx.x;
  const int row0 = blockIdx.x * 64, col0 = blockIdx.y * 64;
  const int tr = tx >> 4, tc = tx & 15;
  const int lr = tx >> 2, lc = (tx & 3) * 4;
  float acc[4][4] = {};
  for (int k0 = 0; k0 < NH; k0 += 16) {
    float4 av = make_float4(0.f, 0.f, 0.f, 0.f);
    if (row0 + lr < Mrows)
      av = *(const float4*)(A + (size_t)(row0 + lr) * NH + k0 + lc);
    float4 bv = *(const float4*)(W1 + (size_t)(col0 + lr) * (NH + NH) + colOff + k0 + lc);
    As[lr][lc] = av.x; As[lr][lc + 1] = av.y; As[lr][lc + 2] = av.z; As[lr][lc + 3] = av.w;
    Bs[lr][lc] = bv.x; Bs[lr][lc + 1] = bv.y; Bs[lr][lc + 2] = bv.z; Bs[lr][lc + 3] = bv.w;
    __syncthreads();
#pragma unroll
    for (int kk = 0; kk < 16; ++kk) {
      float a4[4], b4[4];
#pragma unroll
      for (int i = 0; i < 4; ++i) { a4[i] = As[tr * 4 + i][kk]; b4[i] = Bs[tc * 4 + i][kk]; }
#pragma unroll
      for (int i = 0; i < 4; ++i)
#pragma unroll
        for (int j = 0; j < 4; ++j) acc[i][j] = fmaf(a4[i], b4[j], acc[i][j]);
    }
    __syncthreads();
  }
#pragma unroll
  for (int i = 0; i < 4; ++i) {
    int r = row0 + tr * 4 + i;
    if (r < Mrows) {
#pragma unroll
      for (int j = 0; j < 4; ++j)
        P[(size_t)r * NI + col0 + tc * 4 + j] = acc[i][j];
    }
  }
}

// ---------------------------------------------------------------------------
// W2 f32 -> bf16 bits (1024x512), 4 per thread
// ---------------------------------------------------------------------------
__global__ __launch_bounds__(256) void cvt_w2_kernel(const float* __restrict__ W2,
                                                     unsigned short* __restrict__ w2b) {
  int i = (blockIdx.x * 256 + threadIdx.x) * 4;
  float4 v = *(const float4*)(W2 + i);
  uint2 o;
  o.x = f2bf(v.x) | (f2bf(v.y) << 16);
  o.y = f2bf(v.z) | (f2bf(v.w) << 16);
  *(uint2*)(w2b + i) = o;
}

// ---------------------------------------------------------------------------
// hid[row][i] = bf16(tanh(pe[b,t,i] + pd[b,u,i] + b1[i])), 8 elements/thread
// ---------------------------------------------------------------------------
__global__ __launch_bounds__(256) void hidden_kernel(
    const float* __restrict__ pe, const float* __restrict__ pd,
    const float* __restrict__ b1, unsigned short* __restrict__ hid) {
  int idx = blockIdx.x * 256 + threadIdx.x;   // granule of 8 elements
  int row = idx >> 6;
  int i0 = (idx & 63) * 8;
  int b = row / (NT * NU);
  int rem = row - b * (NT * NU);
  int t = rem / NU;
  int u = rem - t * NU;
  const float* peP = pe + (size_t)(b * NT + t) * NI + i0;
  const float* pdP = pd + (size_t)(b * NU + u) * NI + i0;
  float4 p0 = *(const float4*)peP, p1 = *(const float4*)(peP + 4);
  float4 q0 = *(const float4*)pdP, q1 = *(const float4*)(pdP + 4);
  float4 c0 = *(const float4*)(b1 + i0), c1 = *(const float4*)(b1 + i0 + 4);
  uint4 pk;
  pk.x = f2bf(fast_tanh(p0.x + q0.x + c0.x)) | (f2bf(fast_tanh(p0.y + q0.y + c0.y)) << 16);
  pk.y = f2bf(fast_tanh(p0.z + q0.z + c0.z)) | (f2bf(fast_tanh(p0.w + q0.w + c0.w)) << 16);
  pk.z = f2bf(fast_tanh(p1.x + q1.x + c1.x)) | (f2bf(fast_tanh(p1.y + q1.y + c1.y)) << 16);
  pk.w = f2bf(fast_tanh(p1.z + q1.z + c1.z)) | (f2bf(fast_tanh(p1.w + q1.w + c1.w)) << 16);
  *(uint4*)(hid + (size_t)row * NI + i0) = pk;
}

// ---------------------------------------------------------------------------
// out[r][v] = hid[r][:] . W2[v][:] + b2[v]
// 128x128 tile, BK=64, 4 waves (2x2, wave tile 64x64), mfma_f32_16x16x32_bf16.
// Staging: global_load_lds dwordx4, linear LDS dest; both-sides XOR swizzle
// (inverse-swizzled global src, swizzled ds_read): slot ^= (row&7).
// Grid: bid&7 = vocab tile (one per XCD -> W2 panel L2-resident), bid>>3 = m.
// ---------------------------------------------------------------------------
__global__ __launch_bounds__(256) void gemm_kernel(
    const unsigned short* __restrict__ A,   // hid bf16 [MROWS][512]
    const unsigned short* __restrict__ Bm,  // w2b bf16 [1024][512]
    const float* __restrict__ b2, float* __restrict__ out) {
  __shared__ unsigned char ldsA[16384];   // 128 rows x 64 k x bf16 (128B rows)
  __shared__ unsigned char ldsB[16384];   // 128 cols x 64 k x bf16
  const int tx = threadIdx.x;
  const int bid = blockIdx.x;
  const int nt = bid & 7, mt = bid >> 3;
  const int R0 = mt * 128, C0 = nt * 128;

  const int lane = tx & 63, w = tx >> 6;
  const int wr = w >> 1, wc = w & 1;        // 2x2 wave grid, 64x64 per wave
  const int lr = lane & 15, lq = lane >> 4;

  f32x4 acc[4][4];
#pragma unroll
  for (int mf = 0; mf < 4; ++mf)
#pragma unroll
    for (int nf = 0; nf < 4; ++nf)
#pragma unroll
      for (int z = 0; z < 4; ++z) acc[mf][nf][z] = 0.f;

  for (int kt = 0; kt < 8; ++kt) {
    const int k0 = kt * 64;
    if (kt) __syncthreads();              // prev tile fully consumed
#pragma unroll
    for (int q = 0; q < 4; ++q) {
      int c = q * 256 + tx;               // 16B chunk 0..1023, linear in lane
      int row = c >> 3;                   // 0..127
      int sl = (c & 7) ^ (row & 7);       // logical k-slot stored at this chunk
      gload16(A + (size_t)(R0 + row) * NI + k0 + sl * 8, ldsA + c * 16);
      gload16(Bm + (size_t)(C0 + row) * NI + k0 + sl * 8, ldsB + c * 16);
    }
    __syncthreads();                      // compiler drains vmcnt here

#pragma unroll
    for (int kh8 = 0; kh8 < 8; kh8 += 4) {  // k-halves: slots 0-3, 4-7
      bf16x8 af[4], bfv[4];
#pragma unroll
      for (int f = 0; f < 4; ++f) {
        int row = wr * 64 + f * 16 + lr;
        int sa = (lq + kh8) ^ (row & 7);
        af[f] = *(const bf16x8*)(ldsA + row * 128 + sa * 16);
        int col = wc * 64 + f * 16 + lr;
        int sb = (lq + kh8) ^ (col & 7);
        bfv[f] = *(const bf16x8*)(ldsB + col * 128 + sb * 16);
      }
#pragma unroll
      for (int mf = 0; mf < 4; ++mf)
#pragma unroll
        for (int nf = 0; nf < 4; ++nf)
          acc[mf][nf] = __builtin_amdgcn_mfma_f32_16x16x32_bf16(
              af[mf], bfv[nf], acc[mf][nf], 0, 0, 0);
    }
  }

  // epilogue: + b2, fp32 store (16-lane groups write 64B contiguous)
#pragma unroll
  for (int nf = 0; nf < 4; ++nf) {
    int col = C0 + wc * 64 + nf * 16 + lr;
    float bb = b2[col];
#pragma unroll
    for (int mf = 0; mf < 4; ++mf) {
#pragma unroll
      for (int j = 0; j < 4; ++j) {
        int grow = R0 + wr * 64 + mf * 16 + lq * 4 + j;
        out[(size_t)grow * NV + col] = acc[mf][nf][j] + bb;
      }
    }
  }
}

// ---------------------------------------------------------------------------
// Fallback fused kernel (round-1, used only if ws too small for hid buffer)
// ---------------------------------------------------------------------------
__global__ __launch_bounds__(256, 2) void joint_kernel(
    const float* __restrict__ pe, const float* __restrict__ pd,
    const float* __restrict__ b1, const unsigned short* __restrict__ w2b,
    const float* __restrict__ b2, float* __restrict__ out) {
  __shared__ unsigned short hidS[64 * 512];
  __shared__ unsigned short w2S[128 * 64];
  const int tx = threadIdx.x;
  const int R0 = blockIdx.x * 64;
  uint4 pre[4];
#pragma unroll
  for (int q = 0; q < 4; ++q) {
    int gidx = tx + q * 256;
    int col = gidx >> 3;
    int kbl = (gidx & 7) ^ (col & 7);
    pre[q] = *(const uint4*)(w2b + (size_t)col * NI + kbl * 8);
  }
#pragma unroll 2
  for (int pass = 0; pass < 16; ++pass) {
    int idx = pass * 256 + tx;
    int row = idx >> 6;
    int i0 = (idx & 63) * 8;
    int g = R0 + row;
    int b = g / (NT * NU);
    int rem = g - b * (NT * NU);
    int t = rem / NU;
    int u = rem - t * NU;
    const float* peP = pe + (size_t)(b * NT + t) * NI + i0;
    const float* pdP = pd + (size_t)(b * NU + u) * NI + i0;
    float4 p0 = *(const float4*)peP, p1 = *(const float4*)(peP + 4);
    float4 q0 = *(const float4*)pdP, q1 = *(const float4*)(pdP + 4);
    float4 c0 = *(const float4*)(b1 + i0), c1 = *(const float4*)(b1 + i0 + 4);
    uint4 pk;
    pk.x = f2bf(fast_tanh(p0.x + q0.x + c0.x)) | (f2bf(fast_tanh(p0.y + q0.y + c0.y)) << 16);
    pk.y = f2bf(fast_tanh(p0.z + q0.z + c0.z)) | (f2bf(fast_tanh(p0.w + q0.w + c0.w)) << 16);
    pk.z = f2bf(fast_tanh(p1.x + q1.x + c1.x)) | (f2bf(fast_tanh(p1.y + q1.y + c1.y)) << 16);
    pk.w = f2bf(fast_tanh(p1.z + q1.z + c1.z)) | (f2bf(fast_tanh(p1.w + q1.w + c1.w)) << 16);
    int bo = (row * 1024 + i0 * 2) ^ ((row & 7) << 4);
    *(uint4*)((char*)hidS + bo) = pk;
  }
  const int lane = tx & 63;
  const int w = tx >> 6;
  const int wr = w >> 1, wc = w & 1;
  const int lr = lane & 15, lq = lane >> 4;
  for (int ct = 0; ct < 8; ++ct) {
    const int C0 = ct * 128;
    f32x4 acc[2][4];
#pragma unroll
    for (int rf = 0; rf < 2; ++rf)
#pragma unroll
      for (int cf = 0; cf < 4; ++cf)
#pragma unroll
        for (int z = 0; z < 4; ++z) acc[rf][cf][z] = 0.f;
    for (int ks = 0; ks < 8; ++ks) {
      const int k0 = ks * 64;
      __syncthreads();
#pragma unroll
      for (int q = 0; q < 4; ++q)
        *(uint4*)((char*)w2S + (tx + q * 256) * 16) = pre[q];
      __syncthreads();
      int s = ct * 8 + ks + 1;
      if (s < 64) {
        int nct = s >> 3, nk0 = (s & 7) * 64;
#pragma unroll
        for (int q = 0; q < 4; ++q) {
          int gidx = tx + q * 256;
          int col = gidx >> 3;
          int kbl = (gidx & 7) ^ (col & 7);
          pre[q] = *(const uint4*)(w2b + (size_t)(nct * 128 + col) * NI + nk0 + kbl * 8);
        }
      }
#pragma unroll
      for (int kh = 0; kh < 64; kh += 32) {
        const int ki = k0 + kh + lq * 8;
        bf16x8 afr[2], bfr[4];
#pragma unroll
        for (int rf = 0; rf < 2; ++rf) {
          int row = wr * 32 + rf * 16 + lr;
          int bo = (row * 1024 + ki * 2) ^ ((row & 7) << 4);
          afr[rf] = *(const bf16x8*)((const char*)hidS + bo);
        }
#pragma unroll
        for (int cf = 0; cf < 4; ++cf) {
          int col = wc * 64 + cf * 16 + lr;
          int kk = kh + lq * 8;
          int bo = (col * 128 + kk * 2) ^ ((col & 7) << 4);
          bfr[cf] = *(const bf16x8*)((const char*)w2S + bo);
        }
#pragma unroll
        for (int rf = 0; rf < 2; ++rf)
#pragma unroll
          for (int cf = 0; cf < 4; ++cf)
            acc[rf][cf] = __builtin_amdgcn_mfma_f32_16x16x32_bf16(
                afr[rf], bfr[cf], acc[rf][cf], 0, 0, 0);
      }
    }
#pragma unroll
    for (int cf = 0; cf < 4; ++cf) {
      int col = C0 + wc * 64 + cf * 16 + lr;
      float bb = b2[col];
#pragma unroll
      for (int rf = 0; rf < 2; ++rf) {
#pragma unroll
        for (int j = 0; j < 4; ++j) {
          int grow = R0 + wr * 32 + rf * 16 + lq * 4 + j;
          out[(size_t)grow * NV + col] = acc[rf][cf][j] + bb;
        }
      }
    }
  }
}

extern "C" void kernel_launch(void* const* d_in, const int* in_sizes, int n_in,
                              void* d_out, int out_size, void* d_ws, size_t ws_size,
                              hipStream_t stream) {
  const float* enc = (const float*)d_in[0];
  const float* dec = (const float*)d_in[1];
  const float* W1  = (const float*)d_in[2];
  const float* b1  = (const float*)d_in[3];
  const float* W2  = (const float*)d_in[4];
  const float* b2  = (const float*)d_in[5];
  float* out = (float*)d_out;
  char* ws = (char*)d_ws;

  float* pe = (float*)ws;                                   // 2 MB
  float* pd = (float*)(ws + (2u << 20));                    // 0.8 MB
  unsigned short* w2b = (unsigned short*)(ws + (3u << 20)); // 1 MB
  unsigned short* hid = (unsigned short*)(ws + (4u << 20)); // 100 MB

  const size_t NEED = (4u << 20) + (size_t)MROWS * NI * 2;

  proj_kernel<<<dim3(16, 8), 256, 0, stream>>>(enc, W1, pe, NB * NT, 0);
  proj_kernel<<<dim3(7, 8), 256, 0, stream>>>(dec, W1, pd, NB * NU, NH);
  cvt_w2_kernel<<<512, 256, 0, stream>>>(W2, w2b);

  if (ws_size >= NEED) {
    hidden_kernel<<<MROWS * 64 / 256, 256, 0, stream>>>(pe, pd, b1, hid);
    gemm_kernel<<<(MROWS / 128) * (NV / 128), 256, 0, stream>>>(hid, w2b, b2, out);
  } else {
    joint_kernel<<<1600, 256, 0, stream>>>(pe, pd, b1, w2b, b2, out);
  }
}